// Round 2
// baseline (2641.262 us; speedup 1.0000x reference)
//
#include <hip/hip_runtime.h>

// RoutingCapsules on MI355X (gfx950)
// x: [B=32, Nin=2048, Din=16] f32
// W: [1, Nin=2048, Nout=64, Dout=32, Din=16] f32
// out v: [B=32, Nout=64, Dout=32] f32
//
// 3 fused W-sweeps (u_hat recomputed per pass, never materialized):
//   pass1: c uniform     -> s1 = (1/64) sum_n u_hat        -> v1
//   pass2: logits=u.v1   -> s2                             -> v2
//   pass3: logits=u.(v1+v2)  (b3 = a1+a2)                  -> v3 = out
//
// Round-2 fix: round 1 spilled acc (128 VGPR cap vs ~220 live) -> 1.07 GB/pass
// scratch writes. Now: 1024 thr/block, thread owns (o, 2 d's): w frag 32 regs,
// acc 64 regs, u-stash 16 regs -> fits the forced 128-VGPR cap of a 16-wave block.

#define B_   32
#define NIN  2048
#define DIN  16
#define NOUT 64
#define DOUT 32
#define NCH  8
#define TPB  1024

__device__ __forceinline__ void dot2(const float4* __restrict__ xsrow,
    const float4& w0a, const float4& w0b, const float4& w0c, const float4& w0d,
    const float4& w1a, const float4& w1b, const float4& w1c, const float4& w1d,
    float& u0, float& u1)
{
    float4 xv = xsrow[0];
    u0  = w0a.x*xv.x + w0a.y*xv.y + w0a.z*xv.z + w0a.w*xv.w;
    u1  = w1a.x*xv.x + w1a.y*xv.y + w1a.z*xv.z + w1a.w*xv.w;
    xv = xsrow[1];
    u0 += w0b.x*xv.x + w0b.y*xv.y + w0b.z*xv.z + w0b.w*xv.w;
    u1 += w1b.x*xv.x + w1b.y*xv.y + w1b.z*xv.z + w1b.w*xv.w;
    xv = xsrow[2];
    u0 += w0c.x*xv.x + w0c.y*xv.y + w0c.z*xv.z + w0c.w*xv.w;
    u1 += w1c.x*xv.x + w1c.y*xv.y + w1c.z*xv.z + w1c.w*xv.w;
    xv = xsrow[3];
    u0 += w0d.x*xv.x + w0d.y*xv.y + w0d.z*xv.z + w0d.w*xv.w;
    u1 += w1d.x*xv.x + w1d.y*xv.y + w1d.z*xv.z + w1d.w*xv.w;
}

template<int PASS>
__global__ __launch_bounds__(TPB, 4)
void caps_pass(const float* __restrict__ W, const float* __restrict__ x,
               const float* __restrict__ v_in, float* __restrict__ s_out)
{
    const int t    = threadIdx.x;     // 0..1023
    const int o    = t >> 4;          // 0..63   capsule-out index
    const int dg   = t & 15;          // 0..15
    const int d0   = dg << 1;         // 0,2,..,30  (2 consecutive d's per thread)
    const int lane = t & 63;
    const int nbase = blockIdx.x * NCH;

    __shared__ float4 xs[B_][NCH * DIN / 4];   // [b][nn*4+q], 16 KB
    __shared__ float  lg[2][8][NOUT];          // logit exchange, 4 KB

    // preload the block's x slice once: x[b][nbase..nbase+7][0..15]
    {
        const int b = t >> 5, j = t & 31;      // 32 float4 per b
        xs[b][j] = ((const float4*)x)[(size_t)b * (NIN * DIN / 4) + nbase * (DIN / 4) + j];
    }

    float acc0[B_], acc1[B_];                  // 64 VGPRs, static-indexed
#pragma unroll
    for (int b = 0; b < B_; ++b) { acc0[b] = 0.f; acc1[b] = 0.f; }

    __syncthreads();

    for (int nn = 0; nn < NCH; ++nn) {
        const int n = nbase + nn;
        // W fragment: rows d0, d0+1 of W[n][o] = 32 consecutive floats
        const float4* wp = (const float4*)(W + (((size_t)n * NOUT + o) * DOUT + d0) * DIN);
        const float4 w0a = wp[0], w0b = wp[1], w0c = wp[2], w0d = wp[3];
        const float4 w1a = wp[4], w1b = wp[5], w1c = wp[6], w1d = wp[7];

        if (PASS == 1) {
#pragma unroll
            for (int b = 0; b < B_; ++b) {
                float u0, u1;
                dot2(&xs[b][nn * 4], w0a, w0b, w0c, w0d, w1a, w1b, w1c, w1d, u0, u1);
                acc0[b] += u0;
                acc1[b] += u1;
            }
        } else {
#pragma unroll
            for (int g = 0; g < 4; ++g) {       // b-groups of 8
                float u0r[8], u1r[8];
#pragma unroll
                for (int bb = 0; bb < 8; ++bb) {
                    const int b = g * 8 + bb;
                    float u0, u1;
                    dot2(&xs[b][nn * 4], w0a, w0b, w0c, w0d, w1a, w1b, w1c, w1d, u0, u1);
                    u0r[bb] = u0; u1r[bb] = u1;
                    // logit partial: this thread's 2 d's; v is L2-resident (256 KB)
                    const float2 vv = *(const float2*)&v_in[((size_t)b * NOUT + o) * DOUT + d0];
                    float p = u0 * vv.x + u1 * vv.y;
                    p += __shfl_xor(p, 1);
                    p += __shfl_xor(p, 2);
                    p += __shfl_xor(p, 4);
                    p += __shfl_xor(p, 8);      // full dot over d within 16-lane group
                    if (dg == 0) lg[g & 1][bb][o] = p;
                }
                __syncthreads();
#pragma unroll
                for (int bb = 0; bb < 8; ++bb) {
                    const int b = g * 8 + bb;
                    // softmax over o=64; no max-sub needed (|logit| << 88)
                    float e = __expf(lg[g & 1][bb][lane]);
                    float sm = e;
#pragma unroll
                    for (int m = 1; m < 64; m <<= 1) sm += __shfl_xor(sm, m);
                    const float cw = __shfl(e, o) / sm;
                    acc0[b] += cw * u0r[bb];
                    acc1[b] += cw * u1r[bb];
                }
            }
        }
    }

    const float scale = (PASS == 1) ? (1.0f / 64.0f) : 1.0f;
#pragma unroll
    for (int b = 0; b < B_; ++b) {
        float* dst = &s_out[((size_t)b * NOUT + o) * DOUT + d0];
        atomicAdd(dst,     acc0[b] * scale);
        atomicAdd(dst + 1, acc1[b] * scale);
    }
}

// v = squash(s) per (b,o) row of 32 d; accumulate==1 -> vout += squash(s)
__global__ void squash_k(const float* __restrict__ s, float* __restrict__ vout,
                         int accumulate)
{
    const int idx = blockIdx.x * 256 + threadIdx.x;   // 65536 elements
    const float val = s[idx];
    float sq = val * val;
#pragma unroll
    for (int m = 1; m < 32; m <<= 1) sq += __shfl_xor(sq, m);  // row = 32 lanes
    const float f = sq / ((1.0f + sq) * sqrtf(sq + 1e-8f));
    const float v = val * f;
    if (accumulate) vout[idx] += v;
    else            vout[idx] = v;
}

extern "C" void kernel_launch(void* const* d_in, const int* in_sizes, int n_in,
                              void* d_out, int out_size, void* d_ws, size_t ws_size,
                              hipStream_t stream)
{
    (void)in_sizes; (void)n_in; (void)out_size; (void)ws_size;
    const float* x = (const float*)d_in[0];
    const float* W = (const float*)d_in[1];
    float* out = (float*)d_out;

    float* s  = (float*)d_ws;         // 65536 f32 = 256 KB
    float* vA = s + 65536;            // 65536 f32 = 256 KB (v1, then v1+v2)
    const size_t sbytes = (size_t)65536 * sizeof(float);

    // ---- iter 1: uniform c -> s1 -> v1
    hipMemsetAsync(s, 0, sbytes, stream);
    caps_pass<1><<<dim3(NIN / NCH), dim3(TPB), 0, stream>>>(W, x, nullptr, s);
    squash_k<<<dim3(256), dim3(256), 0, stream>>>(s, vA, 0);      // vA = v1

    // ---- iter 2: logits = u.v1 -> s2 -> v2 ; vA = v1+v2
    hipMemsetAsync(s, 0, sbytes, stream);
    caps_pass<2><<<dim3(NIN / NCH), dim3(TPB), 0, stream>>>(W, x, vA, s);
    squash_k<<<dim3(256), dim3(256), 0, stream>>>(s, vA, 1);      // vA = v1 + v2

    // ---- iter 3: logits = u.(v1+v2) -> s3 -> out = v3
    hipMemsetAsync(s, 0, sbytes, stream);
    caps_pass<2><<<dim3(NIN / NCH), dim3(TPB), 0, stream>>>(W, x, vA, s);
    squash_k<<<dim3(256), dim3(256), 0, stream>>>(s, out, 0);
}